// Round 8
// baseline (904.971 us; speedup 1.0000x reference)
//
#include <hip/hip_runtime.h>

#define N_NODES 100000
#define N_EDGES 1600000
#define IN_DIM 128
#define HID 64
#define OUT_DIM 64

#define NBUCK 782          // dst>>7 buckets of 128 nodes; 782*128=100096>=100000
#define PA_BLOCKS 98       // edge partitions
#define EPB 16384          // edges per partition (98*16384 >= 1.6M)
#define NSCAN (NBUCK * PA_BLOCKS)   // 76636
#define NSCAN4 (NSCAN / 4)          // 19159
#define K1B 1563           // ceil(6250 row-tiles / 4 waves)

typedef __attribute__((ext_vector_type(8))) short short8;
typedef __attribute__((ext_vector_type(4))) float f32x4;
union FragU { short8 v; unsigned u[4]; };

__device__ __forceinline__ unsigned bf16r(float f) {   // fp32 -> bf16 bits, RNE
    unsigned u = __float_as_uint(f);
    return (u + 0x7FFFu + ((u >> 16) & 1u)) >> 16;
}
__device__ __forceinline__ float blo(unsigned u) { return __uint_as_float(u << 16); }
__device__ __forceinline__ float bhi(unsigned u) { return __uint_as_float(u & 0xFFFF0000u); }

// ------- Fused K1 (MFMA linear -> h bf16, s,d fp32) + pA (bucket histogram) ---
// blocks [0,K1B): h/s/d.  blocks [K1B, K1B+98): per-partition LDS histogram of
// dst>>7 into partial[bucket*98 + part].  NO global atomics anywhere.
__global__ __launch_bounds__(256) void k1_pa(const float* __restrict__ x,
                                             const float* __restrict__ W,
                                             const float* __restrict__ att,
                                             uint4* __restrict__ h4,
                                             float* __restrict__ s,
                                             float* __restrict__ d,
                                             const int* __restrict__ ei,
                                             int* __restrict__ partial) {
    __shared__ float wsL[IN_DIM], wdL[IN_DIM];
    __shared__ float scratch[4 * 64 * 17];
    __shared__ int bins[NBUCK];
    const int tid = threadIdx.x;

    if (blockIdx.x >= K1B) {
        // ---- pA: bucket histogram, LDS atomics only ----
        const int part = blockIdx.x - K1B;
        for (int i = tid; i < NBUCK; i += 256) bins[i] = 0;
        __syncthreads();
        const int4* dv4 = (const int4*)(ei + N_EDGES);
        const int base = part * (EPB / 4);
#pragma unroll
        for (int it = 0; it < 16; ++it) {
            int i4 = base + it * 256 + tid;
            if (i4 < N_EDGES / 4) {
                int4 v = dv4[i4];
                atomicAdd(&bins[v.x >> 7], 1);
                atomicAdd(&bins[v.y >> 7], 1);
                atomicAdd(&bins[v.z >> 7], 1);
                atomicAdd(&bins[v.w >> 7], 1);
            }
        }
        __syncthreads();
        for (int k = tid; k < NBUCK; k += 256)
            partial[k * PA_BLOCKS + part] = bins[k];
        return;
    }

    // ---- K1: h = x@W^T via MFMA (bf16); s,d exact fp32 via x@(W^T att) ----
    if (tid < IN_DIM) {
        float as = 0.f, ad = 0.f;
        for (int c = 0; c < HID; ++c) {
            float w = W[c * IN_DIM + tid];
            as += w * att[c];
            ad += w * att[HID + c];
        }
        wsL[tid] = as; wdL[tid] = ad;
    }
    __syncthreads();

    const int lane = tid & 63;
    const int wv = tid >> 6;
    const int l16 = lane & 15;
    const int quad = lane >> 4;
    const int tile = blockIdx.x * 4 + wv;

    FragU bfrag[4][4];
#pragma unroll
    for (int t = 0; t < 4; ++t) {
#pragma unroll
        for (int ks = 0; ks < 4; ++ks) {
            const float* wp = &W[(t * 16 + l16) * IN_DIM + ks * 32 + quad * 8];
            float4 wa = *(const float4*)wp;
            float4 wb = *(const float4*)(wp + 4);
            bfrag[t][ks].u[0] = bf16r(wa.x) | (bf16r(wa.y) << 16);
            bfrag[t][ks].u[1] = bf16r(wa.z) | (bf16r(wa.w) << 16);
            bfrag[t][ks].u[2] = bf16r(wb.x) | (bf16r(wb.y) << 16);
            bfrag[t][ks].u[3] = bf16r(wb.z) | (bf16r(wb.w) << 16);
        }
    }

    if (tile < N_NODES / 16) {
        const int rowbase = tile * 16;
        const float* xrow = &x[(size_t)(rowbase + l16) * IN_DIM];
        f32x4 acc[4] = {{0.f,0.f,0.f,0.f},{0.f,0.f,0.f,0.f},
                        {0.f,0.f,0.f,0.f},{0.f,0.f,0.f,0.f}};
        float ps = 0.f, pd = 0.f;
#pragma unroll
        for (int ks = 0; ks < 4; ++ks) {
            const int k0 = ks * 32 + quad * 8;
            float4 xa = *(const float4*)&xrow[k0];
            float4 xb = *(const float4*)&xrow[k0 + 4];
            ps += xa.x * wsL[k0]     + xa.y * wsL[k0 + 1]
                + xa.z * wsL[k0 + 2] + xa.w * wsL[k0 + 3]
                + xb.x * wsL[k0 + 4] + xb.y * wsL[k0 + 5]
                + xb.z * wsL[k0 + 6] + xb.w * wsL[k0 + 7];
            pd += xa.x * wdL[k0]     + xa.y * wdL[k0 + 1]
                + xa.z * wdL[k0 + 2] + xa.w * wdL[k0 + 3]
                + xb.x * wdL[k0 + 4] + xb.y * wdL[k0 + 5]
                + xb.z * wdL[k0 + 6] + xb.w * wdL[k0 + 7];
            FragU af;
            af.u[0] = bf16r(xa.x) | (bf16r(xa.y) << 16);
            af.u[1] = bf16r(xa.z) | (bf16r(xa.w) << 16);
            af.u[2] = bf16r(xb.x) | (bf16r(xb.y) << 16);
            af.u[3] = bf16r(xb.z) | (bf16r(xb.w) << 16);
#pragma unroll
            for (int t = 0; t < 4; ++t)
                acc[t] = __builtin_amdgcn_mfma_f32_16x16x32_bf16(
                    af.v, bfrag[t][ks].v, acc[t], 0, 0, 0);
        }
        ps += __shfl_xor(ps, 16, 64); ps += __shfl_xor(ps, 32, 64);
        pd += __shfl_xor(pd, 16, 64); pd += __shfl_xor(pd, 32, 64);
        if (quad == 0) { s[rowbase + l16] = ps; d[rowbase + l16] = pd; }
        float* sc = &scratch[wv * 64 * 17];
#pragma unroll
        for (int t = 0; t < 4; ++t)
#pragma unroll
            for (int r = 0; r < 4; ++r)
                sc[(l16 + 16 * t) * 17 + quad * 4 + r] = acc[t][r];
        // same-wave RAW through LDS: compiler inserts lgkmcnt wait
#pragma unroll
        for (int i = 0; i < 2; ++i) {
            int idx = i * 64 + lane;
            int nrow = idx >> 3, q = idx & 7;
            float v0 = sc[(q * 8 + 0) * 17 + nrow];
            float v1 = sc[(q * 8 + 1) * 17 + nrow];
            float v2 = sc[(q * 8 + 2) * 17 + nrow];
            float v3 = sc[(q * 8 + 3) * 17 + nrow];
            float v4 = sc[(q * 8 + 4) * 17 + nrow];
            float v5 = sc[(q * 8 + 5) * 17 + nrow];
            float v6 = sc[(q * 8 + 6) * 17 + nrow];
            float v7 = sc[(q * 8 + 7) * 17 + nrow];
            uint4 o;
            o.x = bf16r(v0) | (bf16r(v1) << 16);
            o.y = bf16r(v2) | (bf16r(v3) << 16);
            o.z = bf16r(v4) | (bf16r(v5) << 16);
            o.w = bf16r(v6) | (bf16r(v7) << 16);
            h4[(size_t)(rowbase + nrow) * 8 + q] = o;
        }
    }
}

// ------- scan: exclusive prefix over partial[76636] (bucket-major) ----------
__global__ __launch_bounds__(1024) void k_scan(const int* __restrict__ partial,
                                               int* __restrict__ scanned) {
    __shared__ int wsum[16];
    __shared__ int carry_s;
    const int tid = threadIdx.x;
    const int lane = tid & 63;
    const int wv = tid >> 6;
    if (tid == 0) carry_s = 0;
    __syncthreads();
    for (int base = 0; base < NSCAN4; base += 2048) {   // 10 chunks
        int i8 = base + tid * 2;
        int4 va = (i8     < NSCAN4) ? ((const int4*)partial)[i8]     : make_int4(0,0,0,0);
        int4 vb = (i8 + 1 < NSCAN4) ? ((const int4*)partial)[i8 + 1] : make_int4(0,0,0,0);
        int t1 = va.x, t2 = t1 + va.y, t3 = t2 + va.z, t4 = t3 + va.w;
        int t5 = t4 + vb.x, t6 = t5 + vb.y, t7 = t6 + vb.z, t8 = t7 + vb.w;
        int sc = t8;
#pragma unroll
        for (int off = 1; off < 64; off <<= 1) {
            int t = __shfl_up(sc, off, 64);
            if (lane >= off) sc += t;
        }
        if (lane == 63) wsum[wv] = sc;
        __syncthreads();
        int wprefix = 0;
#pragma unroll
        for (int w = 0; w < 16; ++w) {
            int t = wsum[w];
            if (w < wv) wprefix += t;
        }
        int excl = carry_s + wprefix + (sc - t8);
        if (i8 < NSCAN4)
            ((int4*)scanned)[i8] = make_int4(excl, excl + t1, excl + t2, excl + t3);
        if (i8 + 1 < NSCAN4)
            ((int4*)scanned)[i8 + 1] = make_int4(excl + t4, excl + t5, excl + t6, excl + t7);
        __syncthreads();
        if (tid == 0) {
            int tot = 0;
#pragma unroll
            for (int w = 0; w < 16; ++w) tot += wsum[w];
            carry_s += tot;
        }
        __syncthreads();
    }
    if (tid == 0) scanned[NSCAN] = carry_s;   // sentinel = N_EDGES
}

// ------- pC: edge attention + bucketed scatter via LDS cursors ---------------
// grid 98; each block owns edge partition [part*EPB, ...), cursors from scan.
__global__ __launch_bounds__(256) void pc_scatter(const int* __restrict__ ei,
                                                  const float* __restrict__ s,
                                                  const float* __restrict__ d,
                                                  const int* __restrict__ scanned,
                                                  uint2* __restrict__ bucketed) {
    __shared__ int cursor[NBUCK];
    const int tid = threadIdx.x;
    const int part = blockIdx.x;
    for (int k = tid; k < NBUCK; k += 256)
        cursor[k] = scanned[k * PA_BLOCKS + part];
    __syncthreads();
    const int4* sv4 = (const int4*)ei;
    const int4* dv4 = (const int4*)(ei + N_EDGES);
    const int base = part * (EPB / 4);
#pragma unroll 2
    for (int it = 0; it < 16; ++it) {
        int i4 = base + it * 256 + tid;
        if (i4 < N_EDGES / 4) {
            int4 sv = sv4[i4];
            int4 dv = dv4[i4];
            float e0 = s[sv.x] + d[dv.x]; e0 = (e0 > 0.f) ? e0 : 0.2f * e0;
            float e1 = s[sv.y] + d[dv.y]; e1 = (e1 > 0.f) ? e1 : 0.2f * e1;
            float e2 = s[sv.z] + d[dv.z]; e2 = (e2 > 0.f) ? e2 : 0.2f * e2;
            float e3 = s[sv.w] + d[dv.w]; e3 = (e3 > 0.f) ? e3 : 0.2f * e3;
            float x0 = __expf(e0), x1 = __expf(e1), x2 = __expf(e2), x3 = __expf(e3);
            int p0 = atomicAdd(&cursor[dv.x >> 7], 1);
            int p1 = atomicAdd(&cursor[dv.y >> 7], 1);
            int p2 = atomicAdd(&cursor[dv.z >> 7], 1);
            int p3 = atomicAdd(&cursor[dv.w >> 7], 1);
            bucketed[p0] = make_uint2((unsigned)((sv.x << 7) | (dv.x & 127)), __float_as_uint(x0));
            bucketed[p1] = make_uint2((unsigned)((sv.y << 7) | (dv.y & 127)), __float_as_uint(x1));
            bucketed[p2] = make_uint2((unsigned)((sv.z << 7) | (dv.z & 127)), __float_as_uint(x2));
            bucketed[p3] = make_uint2((unsigned)((sv.w << 7) | (dv.w & 127)), __float_as_uint(x3));
        }
    }
}

// ------- pD: per-bucket aggregate into LDS fp32, normalize, pack z bf16 ------
// one block per bucket (128 nodes); wave: 4 edge slots x 16 lanes (uint2 = 4ch).
#define ASTR 65
__global__ __launch_bounds__(256) void pd_agg(const uint2* __restrict__ bucketed,
                                              const int* __restrict__ scanned,
                                              const uint2* __restrict__ h2v,
                                              uint4* __restrict__ zp) {
    __shared__ float acc[128 * ASTR];   // 33,280 B, stride 65 breaks bank patterns
    __shared__ float den[128];
    const int tid = threadIdx.x;
    for (int i = tid; i < 128 * ASTR; i += 256) acc[i] = 0.f;
    if (tid < 128) den[tid] = 0.f;
    __syncthreads();
    const int beg = scanned[blockIdx.x * PA_BLOCKS];
    const int endv = scanned[(blockIdx.x + 1) * PA_BLOCKS];  // sentinel-covered
    const int lane = tid & 63;
    const int wv = tid >> 6;
    const int l16 = lane & 15;
    const int grp = lane >> 4;
    int j = beg + wv * 4 + grp;
    for (; j + 16 < endv; j += 32) {            // 8 gathers in flight per wave
        uint2 r0 = bucketed[j];
        uint2 r1 = bucketed[j + 16];
        uint2 g0 = h2v[(r0.x >> 7) * 16u + l16];
        uint2 g1 = h2v[(r1.x >> 7) * 16u + l16];
        float e0 = __uint_as_float(r0.y);
        float e1 = __uint_as_float(r1.y);
        float* a0 = &acc[(r0.x & 127) * ASTR + l16 * 4];
        float* a1 = &acc[(r1.x & 127) * ASTR + l16 * 4];
        atomicAdd(&a0[0], e0 * blo(g0.x));
        atomicAdd(&a0[1], e0 * bhi(g0.x));
        atomicAdd(&a0[2], e0 * blo(g0.y));
        atomicAdd(&a0[3], e0 * bhi(g0.y));
        atomicAdd(&a1[0], e1 * blo(g1.x));
        atomicAdd(&a1[1], e1 * bhi(g1.x));
        atomicAdd(&a1[2], e1 * blo(g1.y));
        atomicAdd(&a1[3], e1 * bhi(g1.y));
        if (l16 == 0) {
            atomicAdd(&den[r0.x & 127], e0);
            atomicAdd(&den[r1.x & 127], e1);
        }
    }
    if (j < endv) {
        uint2 r = bucketed[j];
        uint2 g = h2v[(r.x >> 7) * 16u + l16];
        float e = __uint_as_float(r.y);
        float* a = &acc[(r.x & 127) * ASTR + l16 * 4];
        atomicAdd(&a[0], e * blo(g.x));
        atomicAdd(&a[1], e * bhi(g.x));
        atomicAdd(&a[2], e * blo(g.y));
        atomicAdd(&a[3], e * bhi(g.y));
        if (l16 == 0) atomicAdd(&den[r.x & 127], e);
    }
    __syncthreads();
    const int node0 = blockIdx.x * 128;
    for (int i = tid; i < 128 * 8; i += 256) {   // 1024 uint4 outputs
        int m = i >> 3, q = i & 7;
        int node = node0 + m;
        if (node < N_NODES) {
            float inv = 1.f / (den[m] + 1e-9f);
            const float* a = &acc[m * ASTR + q * 8];
            uint4 o;
            o.x = bf16r(fmaxf(a[0] * inv, 0.f)) | (bf16r(fmaxf(a[1] * inv, 0.f)) << 16);
            o.y = bf16r(fmaxf(a[2] * inv, 0.f)) | (bf16r(fmaxf(a[3] * inv, 0.f)) << 16);
            o.z = bf16r(fmaxf(a[4] * inv, 0.f)) | (bf16r(fmaxf(a[5] * inv, 0.f)) << 16);
            o.w = bf16r(fmaxf(a[6] * inv, 0.f)) | (bf16r(fmaxf(a[7] * inv, 0.f)) << 16);
            zp[(size_t)node * 8 + q] = o;
        }
    }
}

// ------- K4: out = z @ W_out^T + b_out (reg-tiled GEMM) ----------------------
#define K4_M 128
#define ZPAD 133
#define WPAD4 68

__global__ __launch_bounds__(256) void k4_out(const uint2* __restrict__ zp2,
                                              const float* __restrict__ W_out,
                                              const float* __restrict__ b_out,
                                              float* __restrict__ out) {
    __shared__ float zsT[HID * ZPAD];
    __shared__ float wsT[HID * WPAD4];
    const int tid = threadIdx.x;
    const int m0g = blockIdx.x * K4_M;
    for (int i = tid; i < OUT_DIM * HID; i += 256) {
        int c = i >> 6, k = i & 63;
        wsT[k * WPAD4 + c] = W_out[i];
    }
    for (int i = tid; i < K4_M * 16; i += 256) {
        int m = i >> 4, q = i & 15;
        int row = m0g + m;
        uint2 v = (row < N_NODES) ? zp2[row * 16 + q] : make_uint2(0u, 0u);
        int kb = q * 4;
        zsT[(kb + 0) * ZPAD + m] = blo(v.x);
        zsT[(kb + 1) * ZPAD + m] = bhi(v.x);
        zsT[(kb + 2) * ZPAD + m] = blo(v.y);
        zsT[(kb + 3) * ZPAD + m] = bhi(v.y);
    }
    __syncthreads();
    const int m0 = (tid & 31) * 4;
    const int c0 = (tid >> 5) * 8;
    float acc[4][8] = {};
#pragma unroll 4
    for (int k = 0; k < HID; ++k) {
        const float4 zv = *(const float4*)&zsT[k * ZPAD + m0];
        const float4 wa = *(const float4*)&wsT[k * WPAD4 + c0];
        const float4 wb = *(const float4*)&wsT[k * WPAD4 + c0 + 4];
#pragma unroll
        for (int i2 = 0; i2 < 4; ++i2) {
            float zi = (&zv.x)[i2];
            acc[i2][0] += zi * wa.x; acc[i2][1] += zi * wa.y;
            acc[i2][2] += zi * wa.z; acc[i2][3] += zi * wa.w;
            acc[i2][4] += zi * wb.x; acc[i2][5] += zi * wb.y;
            acc[i2][6] += zi * wb.z; acc[i2][7] += zi * wb.w;
        }
    }
    const float4 b0 = *(const float4*)&b_out[c0];
    const float4 b1 = *(const float4*)&b_out[c0 + 4];
#pragma unroll
    for (int i2 = 0; i2 < 4; ++i2) {
        int row = m0g + m0 + i2;
        if (row < N_NODES) {
            *(float4*)&out[row * OUT_DIM + c0] =
                make_float4(acc[i2][0] + b0.x, acc[i2][1] + b0.y,
                            acc[i2][2] + b0.z, acc[i2][3] + b0.w);
            *(float4*)&out[row * OUT_DIM + c0 + 4] =
                make_float4(acc[i2][4] + b1.x, acc[i2][5] + b1.y,
                            acc[i2][6] + b1.z, acc[i2][7] + b1.w);
        }
    }
}

extern "C" void kernel_launch(void* const* d_in, const int* in_sizes, int n_in,
                              void* d_out, int out_size, void* d_ws, size_t ws_size,
                              hipStream_t stream) {
    const float* x     = (const float*)d_in[0];
    const int*   ei    = (const int*)d_in[1];
    const float* W_lin = (const float*)d_in[2];
    const float* att   = (const float*)d_in[3];
    const float* W_out = (const float*)d_in[4];
    const float* b_out = (const float*)d_in[5];
    float* out = (float*)d_out;

    // workspace layout (~39.8 MB, 16B-aligned). No memsets needed: every
    // buffer is fully written before it is read.
    char* ws = (char*)d_ws;
    unsigned* h2       = (unsigned*)(ws);                 // 12,800,000 B (bf16 h)
    float*    s        = (float*)(ws + 12800000);         //    400,000 B
    float*    d        = (float*)(ws + 13200000);         //    400,000 B
    int*      partial  = (int*)  (ws + 13600000);         //    306,544 B
    int*      scanned  = (int*)  (ws + 13906544);         //    306,548 B (+sentinel)
    uint2*    bucketed = (uint2*)(ws + 14213104);         // 12,800,000 B
    unsigned* zp       = (unsigned*)(ws + 27013104);      // 12,800,000 B (bf16 z)

    k1_pa<<<K1B + PA_BLOCKS, 256, 0, stream>>>(
        x, W_lin, att, (uint4*)h2, s, d, ei, partial);
    k_scan<<<1, 1024, 0, stream>>>(partial, scanned);
    pc_scatter<<<PA_BLOCKS, 256, 0, stream>>>(ei, s, d, scanned, bucketed);
    pd_agg<<<NBUCK, 256, 0, stream>>>(bucketed, scanned, (const uint2*)h2, (uint4*)zp);
    k4_out<<<(N_NODES + K4_M - 1) / K4_M, 256, 0, stream>>>(
        (const uint2*)zp, W_out, b_out, out);
}